// Round 3
// baseline (600.405 us; speedup 1.0000x reference)
//
#include <hip/hip_runtime.h>
#include <math.h>

#ifndef INFINITY
#define INFINITY __builtin_inff()
#endif

#define EPS 1e-6f
#define K4PI2 0.405284734569351086f  // 4 / pi^2

constexpr int B = 64;
constexpr int N = 25200;
constexpr int D = 21;
constexpr int G = 32;
constexpr int CHUNKS = 16;
constexpr int CHUNK = (N + CHUNKS - 1) / CHUNKS;  // 1575
constexpr int BLK = 256;
constexpr int GB = 16;      // gts per block (G split across blockIdx.y)
constexpr int GSPLIT = G / GB;

// dword-aligned vector load type (pred rows are 84B-strided: only 4B-aligned)
typedef float f32x4u __attribute__((ext_vector_type(4), aligned(4)));

__device__ __forceinline__ float fastrcp(float x) {
    return __builtin_amdgcn_rcpf(x);  // ~1 ulp; scores only feed argmax
}

__device__ __forceinline__ float softplusf(float x) {
    return fmaxf(x, 0.0f) + log1pf(expf(-fabsf(x)));  // stable log(1+e^x)
}

// Full-reference-order CIoU with IEEE division (only for the 2048 final terms).
__device__ __forceinline__ float ciou_exact(float p_cx, float p_cy, float pw, float ph,
                                            float g_cx, float g_cy, float gw, float gh) {
    float p_x1 = p_cx - pw * 0.5f, p_y1 = p_cy - ph * 0.5f;
    float p_x2 = p_cx + pw * 0.5f, p_y2 = p_cy + ph * 0.5f;
    float g_x1 = g_cx - gw * 0.5f, g_y1 = g_cy - gh * 0.5f;
    float g_x2 = g_cx + gw * 0.5f, g_y2 = g_cy + gh * 0.5f;
    float iw = fmaxf(fminf(p_x2, g_x2) - fmaxf(p_x1, g_x1), 0.0f);
    float ih = fmaxf(fminf(p_y2, g_y2) - fmaxf(p_y1, g_y1), 0.0f);
    float inter = iw * ih;
    float p_area = (p_x2 - p_x1) * (p_y2 - p_y1);
    float g_area = (g_x2 - g_x1) * (g_y2 - g_y1);
    float uni = p_area + g_area - inter;
    float iou = inter / (uni + EPS);
    float dx = p_cx - g_cx, dy = p_cy - g_cy;
    float cd = dx * dx + dy * dy;
    float ew = fmaxf(p_x2, g_x2) - fminf(p_x1, g_x1);
    float eh = fmaxf(p_y2, g_y2) - fminf(p_y1, g_y1);
    float ed = ew * ew + eh * eh;
    float dat = atanf(pw / ph) - atanf(gw / gh);
    float v = K4PI2 * (dat * dat);
    float alpha = v / (1.0f - iou + v + EPS);
    return iou - cd / (ed + EPS) - alpha * v;
}

// Phase 1: per (batch, chunk, g-half) block: per-gt argmax of CIoU over chunk preds.
// 16 gts/block keeps trackers+hoisted constants under the 128-VGPR / 4-waves-per-EU cap.
__global__ __launch_bounds__(BLK, 4) void k_argmax(const float* __restrict__ preds,
                                                   const float* __restrict__ gt_boxes,
                                                   float* __restrict__ pval,
                                                   int* __restrict__ pidx) {
    __shared__ float4 gA[GB];  // x1, y1, x2, y2
    __shared__ float4 gQ[GB];  // cx, cy, area, atan(w/h)
    __shared__ float2 gW[GB];  // gw' = x2-x1, gh' = y2-y1  (for enc identity)
    __shared__ float sval[BLK / 64][GB];
    __shared__ int sidx[BLK / 64][GB];

    const int b = blockIdx.x / CHUNKS;
    const int chunk = blockIdx.x % CHUNKS;
    const int g0 = blockIdx.y * GB;
    const int tid = threadIdx.x;

    if (tid < GB) {
        const float* gb = gt_boxes + ((size_t)b * G + g0 + tid) * 4;
        float cx = gb[0], cy = gb[1], w = gb[2], h = gb[3];
        float x1 = cx - w * 0.5f, y1 = cy - h * 0.5f;
        float x2 = cx + w * 0.5f, y2 = cy + h * 0.5f;
        float gw = x2 - x1, gh = y2 - y1;
        gA[tid] = make_float4(x1, y1, x2, y2);
        gQ[tid] = make_float4(cx, cy, gw * gh, atanf(w / h));
        gW[tid] = make_float2(gw, gh);
    }
    __syncthreads();

    float bestv[GB];
    int besti[GB];
#pragma unroll
    for (int g = 0; g < GB; ++g) { bestv[g] = -INFINITY; besti[g] = 0x7fffffff; }

    const int n0 = chunk * CHUNK;
    const int n1 = (n0 + CHUNK < N) ? (n0 + CHUNK) : N;
    for (int n = n0 + tid; n < n1; n += BLK) {
        const f32x4u pr = *reinterpret_cast<const f32x4u*>(preds + ((size_t)b * N + n) * D);
        float cx = pr.x, cy = pr.y, w = pr.z, h = pr.w;
        float px1 = cx - w * 0.5f, py1 = cy - h * 0.5f;
        float px2 = cx + w * 0.5f, py2 = cy + h * 0.5f;
        float pw = px2 - px1, ph = py2 - py1;
        float pareaplus = pw * ph + EPS;
        float pat = atanf(w / h);
#pragma unroll
        for (int g = 0; g < GB; ++g) {
            float4 a = gA[g];
            float4 q = gQ[g];
            float2 c = gW[g];
            // intersection (raw, pre-clamp reused for enclosure via min+max=sum identity)
            float iw_raw = fminf(px2, a.z) - fmaxf(px1, a.x);
            float ih_raw = fminf(py2, a.w) - fmaxf(py1, a.y);
            float inter = fmaxf(iw_raw, 0.0f) * fmaxf(ih_raw, 0.0f);
            float uni = (q.z + pareaplus) - inter;
            float iou = inter * fastrcp(uni);
            float dx = cx - q.x, dy = cy - q.y;
            float cd = dx * dx + dy * dy;
            float ew = (pw + c.x) - iw_raw;   // = max(px2,gx2) - min(px1,gx1)
            float eh = (ph + c.y) - ih_raw;
            float ed = ew * ew + eh * eh + EPS;
            float dat = pat - q.w;
            float v = K4PI2 * (dat * dat);
            float den = (1.0f + EPS) + v - iou;
            float ciou = iou - cd * fastrcp(ed) - (v * v) * fastrcp(den);
            if (ciou > bestv[g]) { bestv[g] = ciou; besti[g] = n; }
        }
    }

    // wave argmax reduce, tie -> lower index (jnp.argmax first-occurrence)
    const int lane = tid & 63;
    const int wid = tid >> 6;
#pragma unroll
    for (int g = 0; g < GB; ++g) {
        float v = bestv[g];
        int i = besti[g];
#pragma unroll
        for (int off = 32; off > 0; off >>= 1) {
            float ov = __shfl_down(v, off);
            int oi = __shfl_down(i, off);
            if (ov > v || (ov == v && oi < i)) { v = ov; i = oi; }
        }
        if (lane == 0) { sval[wid][g] = v; sidx[wid][g] = i; }
    }
    __syncthreads();

    if (tid < GB) {
        float v = sval[0][tid];
        int i = sidx[0][tid];
#pragma unroll
        for (int w = 1; w < BLK / 64; ++w) {
            float ov = sval[w][tid];
            int oi = sidx[w][tid];
            if (ov > v || (ov == v && oi < i)) { v = ov; i = oi; }
        }
        size_t o = ((size_t)b * G + g0 + tid) * CHUNKS + chunk;
        pval[o] = v;
        pidx[o] = i;
    }
}

// Phase 2 (fused final): one block; reduce chunk partials, gather matched preds,
// exact loss, block-reduce, write scalar.
__global__ __launch_bounds__(1024) void k_loss(const float* __restrict__ preds,
                                               const float* __restrict__ gt_boxes,
                                               const int* __restrict__ gt_cls,
                                               const float* __restrict__ pval,
                                               const int* __restrict__ pidx,
                                               float* __restrict__ out) {
    __shared__ float red[16];
    const int tid = threadIdx.x;
    float acc = 0.0f;
    for (int item = tid; item < B * G; item += 1024) {
        const int b = item >> 5;
        const int g = item & (G - 1);
        size_t base = (size_t)item * CHUNKS;
        float v = pval[base];
        int i = pidx[base];
#pragma unroll
        for (int c = 1; c < CHUNKS; ++c) {
            float ov = pval[base + c];
            int oi = pidx[base + c];
            if (ov > v || (ov == v && oi < i)) { v = ov; i = oi; }
        }
        const float* pr = preds + ((size_t)b * N + i) * D;
        const f32x4u p4 = *reinterpret_cast<const f32x4u*>(pr);
        const float* gb = gt_boxes + ((size_t)b * G + g) * 4;
        float ciou = ciou_exact(p4.x, p4.y, p4.z, p4.w, gb[0], gb[1], gb[2], gb[3]);
        float loss_box = 1.0f - ciou;
        float loss_obj = softplusf(-pr[4]);
        int cls = gt_cls[b * G + g];
        float loss_cls = softplusf(-pr[5 + cls]);
        acc += 5.0f * loss_box + loss_obj + loss_cls;
    }
#pragma unroll
    for (int off = 32; off > 0; off >>= 1) acc += __shfl_down(acc, off);
    if ((tid & 63) == 0) red[tid >> 6] = acc;
    __syncthreads();
    if (tid == 0) {
        float s = 0.0f;
#pragma unroll
        for (int w = 0; w < 16; ++w) s += red[w];
        out[0] = s;
    }
}

extern "C" void kernel_launch(void* const* d_in, const int* in_sizes, int n_in,
                              void* d_out, int out_size, void* d_ws, size_t ws_size,
                              hipStream_t stream) {
    const float* preds = (const float*)d_in[0];
    const float* gt_boxes = (const float*)d_in[1];
    const int* gt_cls = (const int*)d_in[2];
    float* out = (float*)d_out;

    float* pval = (float*)d_ws;  // B*G*CHUNKS f32
    int* pidx = (int*)((char*)d_ws + sizeof(float) * (size_t)B * G * CHUNKS);

    k_argmax<<<dim3(B * CHUNKS, GSPLIT), BLK, 0, stream>>>(preds, gt_boxes, pval, pidx);
    k_loss<<<1, 1024, 0, stream>>>(preds, gt_boxes, gt_cls, pval, pidx, out);
}

// Round 5
// 294.181 us; speedup vs baseline: 2.0409x; 2.0409x over previous
//
#include <hip/hip_runtime.h>
#include <math.h>

#ifndef INFINITY
#define INFINITY __builtin_inff()
#endif

#define EPS 1e-6f
#define K4PI2 0.405284734569351086f  // 4 / pi^2

constexpr int B = 64;
constexpr int N = 25200;
constexpr int D = 21;
constexpr int G = 32;
constexpr int CHUNKS = 16;
constexpr int CHUNK = (N + CHUNKS - 1) / CHUNKS;  // 1575
constexpr int BLK = 256;
constexpr int GB = 8;                 // gts per block: 8*10 hoisted + 16 trackers fits <168 VGPR
constexpr int GSPLIT = G / GB;        // 4
static_assert(GSPLIT == 4, "g0 decode uses & 3");

// dword-aligned vector load (pred rows are 84B-strided: only 4B-aligned)
typedef float f32x4u __attribute__((ext_vector_type(4), aligned(4)));

__device__ __forceinline__ float fastrcp(float x) {
    return __builtin_amdgcn_rcpf(x);  // ~1 ulp; phase-1 scores only feed argmax
}

__device__ __forceinline__ float softplusf(float x) {
    return fmaxf(x, 0.0f) + log1pf(expf(-fabsf(x)));  // stable log(1+e^x)
}

// Full-reference-order CIoU with IEEE division (only for the 2048 final terms).
__device__ __forceinline__ float ciou_exact(float p_cx, float p_cy, float pw, float ph,
                                            float g_cx, float g_cy, float gw, float gh) {
    float p_x1 = p_cx - pw * 0.5f, p_y1 = p_cy - ph * 0.5f;
    float p_x2 = p_cx + pw * 0.5f, p_y2 = p_cy + ph * 0.5f;
    float g_x1 = g_cx - gw * 0.5f, g_y1 = g_cy - gh * 0.5f;
    float g_x2 = g_cx + gw * 0.5f, g_y2 = g_cy + gh * 0.5f;
    float iw = fmaxf(fminf(p_x2, g_x2) - fmaxf(p_x1, g_x1), 0.0f);
    float ih = fmaxf(fminf(p_y2, g_y2) - fmaxf(p_y1, g_y1), 0.0f);
    float inter = iw * ih;
    float p_area = (p_x2 - p_x1) * (p_y2 - p_y1);
    float g_area = (g_x2 - g_x1) * (g_y2 - g_y1);
    float uni = p_area + g_area - inter;
    float iou = inter / (uni + EPS);
    float dx = p_cx - g_cx, dy = p_cy - g_cy;
    float cd = dx * dx + dy * dy;
    float ew = fmaxf(p_x2, g_x2) - fminf(p_x1, g_x1);
    float eh = fmaxf(p_y2, g_y2) - fminf(p_y1, g_y1);
    float ed = ew * ew + eh * eh;
    float dat = atanf(pw / ph) - atanf(gw / gh);
    float v = K4PI2 * (dat * dat);
    float alpha = v / (1.0f - iou + v + EPS);
    return iou - cd / (ed + EPS) - alpha * v;
}

// Phase 1: per (g-group, batch, chunk) block: per-gt argmax of CIoU over chunk preds.
// g-group in the LOW bits of blockIdx so the 4 passes over the same pred lines are
// dispatched adjacently (L2/L3 reuse). (256,3): 168-VGPR cap — fits ~130 live, no spill.
__global__ __launch_bounds__(BLK, 3) void k_argmax(const float* __restrict__ preds,
                                                   const float* __restrict__ gt_boxes,
                                                   float* __restrict__ pval,
                                                   int* __restrict__ pidx) {
    __shared__ float4 gA[GB];  // x1, y1, x2, y2
    __shared__ float4 gQ[GB];  // cx, cy, area, atan(w/h)
    __shared__ float2 gW[GB];  // gw' = x2-x1, gh' = y2-y1  (for enc identity)
    __shared__ float sval[BLK / 64][GB];
    __shared__ int sidx[BLK / 64][GB];

    const int bid = blockIdx.x;
    const int g0 = (bid & 3) * GB;
    const int bc = bid >> 2;
    const int b = bc / CHUNKS;
    const int chunk = bc % CHUNKS;
    const int tid = threadIdx.x;

    if (tid < GB) {
        const float* gb = gt_boxes + ((size_t)b * G + g0 + tid) * 4;
        float cx = gb[0], cy = gb[1], w = gb[2], h = gb[3];
        float x1 = cx - w * 0.5f, y1 = cy - h * 0.5f;
        float x2 = cx + w * 0.5f, y2 = cy + h * 0.5f;
        float gw = x2 - x1, gh = y2 - y1;
        gA[tid] = make_float4(x1, y1, x2, y2);
        gQ[tid] = make_float4(cx, cy, gw * gh, atanf(w / h));
        gW[tid] = make_float2(gw, gh);
    }
    __syncthreads();

    float bestv[GB];
    int besti[GB];
#pragma unroll
    for (int g = 0; g < GB; ++g) { bestv[g] = -INFINITY; besti[g] = 0x7fffffff; }

    const int n0 = chunk * CHUNK;
    const int n1 = (n0 + CHUNK < N) ? (n0 + CHUNK) : N;
    for (int n = n0 + tid; n < n1; n += BLK) {
        const f32x4u pr = *reinterpret_cast<const f32x4u*>(preds + ((size_t)b * N + n) * D);
        float cx = pr.x, cy = pr.y, w = pr.z, h = pr.w;
        float px1 = cx - w * 0.5f, py1 = cy - h * 0.5f;
        float px2 = cx + w * 0.5f, py2 = cy + h * 0.5f;
        float pw = px2 - px1, ph = py2 - py1;
        float pareaplus = pw * ph + EPS;
        float pat = atanf(w / h);
#pragma unroll
        for (int g = 0; g < GB; ++g) {
            float4 a = gA[g];
            float4 q = gQ[g];
            float2 c = gW[g];
            float iw_raw = fminf(px2, a.z) - fmaxf(px1, a.x);
            float ih_raw = fminf(py2, a.w) - fmaxf(py1, a.y);
            float inter = fmaxf(iw_raw, 0.0f) * fmaxf(ih_raw, 0.0f);
            float uni = (q.z + pareaplus) - inter;
            float iou = inter * fastrcp(uni);
            float dx = cx - q.x, dy = cy - q.y;
            float cd = dx * dx + dy * dy;
            float ew = (pw + c.x) - iw_raw;   // = max(px2,gx2) - min(px1,gx1)
            float eh = (ph + c.y) - ih_raw;
            float ed = ew * ew + eh * eh + EPS;
            float dat = pat - q.w;
            float v = K4PI2 * (dat * dat);
            float den = (1.0f + EPS) + v - iou;
            float ciou = iou - cd * fastrcp(ed) - (v * v) * fastrcp(den);
            if (ciou > bestv[g]) { bestv[g] = ciou; besti[g] = n; }
        }
    }

    // wave argmax reduce, tie -> lower index (jnp.argmax first-occurrence)
    const int lane = tid & 63;
    const int wid = tid >> 6;
#pragma unroll
    for (int g = 0; g < GB; ++g) {
        float v = bestv[g];
        int i = besti[g];
#pragma unroll
        for (int off = 32; off > 0; off >>= 1) {
            float ov = __shfl_down(v, off);
            int oi = __shfl_down(i, off);
            if (ov > v || (ov == v && oi < i)) { v = ov; i = oi; }
        }
        if (lane == 0) { sval[wid][g] = v; sidx[wid][g] = i; }
    }
    __syncthreads();

    if (tid < GB) {
        float v = sval[0][tid];
        int i = sidx[0][tid];
#pragma unroll
        for (int w = 1; w < BLK / 64; ++w) {
            float ov = sval[w][tid];
            int oi = sidx[w][tid];
            if (ov > v || (ov == v && oi < i)) { v = ov; i = oi; }
        }
        size_t o = ((size_t)b * G + g0 + tid) * CHUNKS + chunk;
        pval[o] = v;
        pidx[o] = i;
    }
}

// Phase 2: per-batch block; reduce chunk partials, gather matched preds, exact loss.
__global__ __launch_bounds__(64) void k_loss(const float* __restrict__ preds,
                                             const float* __restrict__ gt_boxes,
                                             const int* __restrict__ gt_cls,
                                             const float* __restrict__ pval,
                                             const int* __restrict__ pidx,
                                             float* __restrict__ partial) {
    const int b = blockIdx.x;
    const int tid = threadIdx.x;
    float contrib = 0.0f;
    if (tid < G) {
        const int g = tid;
        size_t base = ((size_t)b * G + g) * CHUNKS;
        float v = pval[base];
        int i = pidx[base];
#pragma unroll
        for (int c = 1; c < CHUNKS; ++c) {
            float ov = pval[base + c];
            int oi = pidx[base + c];
            if (ov > v || (ov == v && oi < i)) { v = ov; i = oi; }
        }
        const float* pr = preds + ((size_t)b * N + i) * D;
        const f32x4u p4 = *reinterpret_cast<const f32x4u*>(pr);
        const float* gb = gt_boxes + ((size_t)b * G + g) * 4;
        float ciou = ciou_exact(p4.x, p4.y, p4.z, p4.w, gb[0], gb[1], gb[2], gb[3]);
        float loss_box = 1.0f - ciou;
        float loss_obj = softplusf(-pr[4]);
        int cls = gt_cls[b * G + g];
        float loss_cls = softplusf(-pr[5 + cls]);
        contrib = 5.0f * loss_box + loss_obj + loss_cls;
    }
#pragma unroll
    for (int off = 32; off > 0; off >>= 1) contrib += __shfl_down(contrib, off);
    if (tid == 0) partial[b] = contrib;
}

// Phase 3: sum 64 per-batch partials into the scalar output.
__global__ __launch_bounds__(64) void k_final(const float* __restrict__ partial,
                                              float* __restrict__ out) {
    float v = partial[threadIdx.x];
#pragma unroll
    for (int off = 32; off > 0; off >>= 1) v += __shfl_down(v, off);
    if (threadIdx.x == 0) out[0] = v;
}

extern "C" void kernel_launch(void* const* d_in, const int* in_sizes, int n_in,
                              void* d_out, int out_size, void* d_ws, size_t ws_size,
                              hipStream_t stream) {
    const float* preds = (const float*)d_in[0];
    const float* gt_boxes = (const float*)d_in[1];
    const int* gt_cls = (const int*)d_in[2];
    float* out = (float*)d_out;

    float* pval = (float*)d_ws;  // B*G*CHUNKS f32
    int* pidx = (int*)((char*)d_ws + sizeof(float) * (size_t)B * G * CHUNKS);
    float* partial = (float*)((char*)d_ws + 2 * sizeof(float) * (size_t)B * G * CHUNKS);

    k_argmax<<<B * CHUNKS * GSPLIT, BLK, 0, stream>>>(preds, gt_boxes, pval, pidx);
    k_loss<<<B, 64, 0, stream>>>(preds, gt_boxes, gt_cls, pval, pidx, partial);
    k_final<<<1, 64, 0, stream>>>(partial, out);
}

// Round 7
// 239.621 us; speedup vs baseline: 2.5056x; 1.2277x over previous
//
#include <hip/hip_runtime.h>
#include <math.h>

#ifndef INFINITY
#define INFINITY __builtin_inff()
#endif

#define EPS 1e-6f
#define K4PI2 0.405284734569351086f  // 4 / pi^2

constexpr int B = 64;
constexpr int N = 25200;
constexpr int D = 21;
constexpr int G = 32;
constexpr int CHUNKS = 16;
constexpr int CHUNK = N / CHUNKS;   // 1575 (exact: 16*1575 = 25200)
constexpr int BLK = 512;            // 8 waves
constexpr int TILE = 512;           // preds staged per LDS tile
constexpr int NW = BLK / 64;        // 8
constexpr int STREAMS = NW * 2;     // 16 pred-streams (2 per wave: half-wave each)

// dword-aligned vector load (pred rows are 84B-strided: only 4B-aligned)
typedef float f32x4u __attribute__((ext_vector_type(4), aligned(4)));

__device__ __forceinline__ float fastrcp(float x) {
    return __builtin_amdgcn_rcpf(x);  // ~1 ulp; phase-1 scores only feed argmax
}

__device__ __forceinline__ float softplusf(float x) {
    return fmaxf(x, 0.0f) + log1pf(expf(-fabsf(x)));  // stable log(1+e^x)
}

// Full-reference-order CIoU with IEEE division (only for the 2048 final terms).
__device__ __forceinline__ float ciou_exact(float p_cx, float p_cy, float pw, float ph,
                                            float g_cx, float g_cy, float gw, float gh) {
    float p_x1 = p_cx - pw * 0.5f, p_y1 = p_cy - ph * 0.5f;
    float p_x2 = p_cx + pw * 0.5f, p_y2 = p_cy + ph * 0.5f;
    float g_x1 = g_cx - gw * 0.5f, g_y1 = g_cy - gh * 0.5f;
    float g_x2 = g_cx + gw * 0.5f, g_y2 = g_cy + gh * 0.5f;
    float iw = fmaxf(fminf(p_x2, g_x2) - fmaxf(p_x1, g_x1), 0.0f);
    float ih = fmaxf(fminf(p_y2, g_y2) - fmaxf(p_y1, g_y1), 0.0f);
    float inter = iw * ih;
    float p_area = (p_x2 - p_x1) * (p_y2 - p_y1);
    float g_area = (g_x2 - g_x1) * (g_y2 - g_y1);
    float uni = p_area + g_area - inter;
    float iou = inter / (uni + EPS);
    float dx = p_cx - g_cx, dy = p_cy - g_cy;
    float cd = dx * dx + dy * dy;
    float ew = fmaxf(p_x2, g_x2) - fminf(p_x1, g_x1);
    float eh = fmaxf(p_y2, g_y2) - fminf(p_y1, g_y1);
    float ed = ew * ew + eh * eh;
    float dat = atanf(pw / ph) - atanf(gw / gh);
    float v = K4PI2 * (dat * dat);
    float alpha = v / (1.0f - iou + v + EPS);
    return iou - cd / (ed + EPS) - alpha * v;
}

// Phase 1: gt <-> lane mapping. Lane l owns gt (l & 31) as scalar registers.
// Preds staged through LDS (global latency decoupled; atanf once per pred, total).
// Each wave handles 2 preds/iter (one per half-wave, broadcast ds_read).
// Preds are read from HBM exactly once (no g-split re-reads).
__global__ __launch_bounds__(BLK, 6) void k_argmax(const float* __restrict__ preds,
                                                   const float* __restrict__ gt_boxes,
                                                   float* __restrict__ pval,
                                                   int* __restrict__ pidx) {
    __shared__ float4 sA[TILE];   // px1, py1, px2, py2
    __shared__ float4 sB[TILE];   // pw, ph, parea+EPS, atan(w/h)
    __shared__ float2 sC[TILE];   // pcx, pcy
    __shared__ float rv[NW][G];
    __shared__ int ri[NW][G];

    const int b = blockIdx.x / CHUNKS;
    const int chunk = blockIdx.x % CHUNKS;
    const int tid = threadIdx.x;
    const int lane = tid & 63;
    const int wid = tid >> 6;
    const int g = lane & 31;
    const int stream = wid * 2 + (lane >> 5);  // 0..15

    // per-lane gt constants (lanes l and l+32 duplicate gt l's regs — by design)
    const float4 gt4 = *reinterpret_cast<const float4*>(gt_boxes + ((size_t)b * G + g) * 4);
    const float gcx = gt4.x, gcy = gt4.y;
    const float gx1 = gcx - gt4.z * 0.5f, gy1 = gcy - gt4.w * 0.5f;
    const float gx2 = gcx + gt4.z * 0.5f, gy2 = gcy + gt4.w * 0.5f;
    const float gww = gx2 - gx1, ghh = gy2 - gy1;
    const float garea = gww * ghh;
    const float gat = atanf(gt4.z / gt4.w);

    float bestv = -INFINITY;
    int besti = 0x7fffffff;

    const int n0 = chunk * CHUNK;
    const float qnan = __builtin_nanf("");

    for (int t0 = 0; t0 < CHUNK; t0 += TILE) {
        // ---- stage TILE preds (one per thread) ----
        {
            const int p = t0 + tid;
            if (p < CHUNK) {
                const int n = n0 + p;
                const f32x4u pr =
                    *reinterpret_cast<const f32x4u*>(preds + ((size_t)b * N + n) * D);
                float cx = pr.x, cy = pr.y, w = pr.z, h = pr.w;
                float px1 = cx - w * 0.5f, py1 = cy - h * 0.5f;
                float px2 = cx + w * 0.5f, py2 = cy + h * 0.5f;
                float pw = px2 - px1, ph = py2 - py1;
                sA[tid] = make_float4(px1, py1, px2, py2);
                sB[tid] = make_float4(pw, ph, pw * ph + EPS, atanf(w / h));
                sC[tid] = make_float2(cx, cy);
            } else {
                sA[tid] = make_float4(qnan, qnan, qnan, qnan);
                sB[tid] = make_float4(qnan, qnan, qnan, qnan);
                sC[tid] = make_float2(qnan, qnan);
            }
        }
        __syncthreads();

        const int nbase = n0 + t0;
#pragma unroll 8
        for (int it = 0; it < TILE / STREAMS; ++it) {
            const int pp = it * STREAMS + stream;  // uniform per half-wave -> broadcast
            const float4 A = sA[pp];
            const float4 Bv = sB[pp];
            const float2 C2 = sC[pp];
            float iw = fminf(A.z, gx2) - fmaxf(A.x, gx1);
            float ih = fminf(A.w, gy2) - fmaxf(A.y, gy1);
            float inter = fmaxf(iw, 0.0f) * fmaxf(ih, 0.0f);
            float uni = (garea + Bv.z) - inter;
            float iou = inter * fastrcp(uni);
            float dx = C2.x - gcx, dy = C2.y - gcy;
            float cd = dx * dx + dy * dy;
            float ew = (Bv.x + gww) - iw;   // = max(px2,gx2) - min(px1,gx1)
            float eh = (Bv.y + ghh) - ih;
            float ed = ew * ew + eh * eh + EPS;
            float dat = Bv.w - gat;
            float v = K4PI2 * (dat * dat);
            float den = (1.0f + EPS) + v - iou;
            float ciou = iou - cd * fastrcp(ed) - (v * v) * fastrcp(den);
            // NaN (padding) compares false -> never selected
            if (ciou > bestv) { bestv = ciou; besti = nbase + pp; }
        }
        __syncthreads();
    }

    // combine the two half-wave streams (same g, disjoint preds)
    {
        float ov = __shfl_down(bestv, 32);
        int oi = __shfl_down(besti, 32);
        if (ov > bestv || (ov == bestv && oi < besti)) { bestv = ov; besti = oi; }
        if (lane < 32) { rv[wid][g] = bestv; ri[wid][g] = besti; }
    }
    __syncthreads();

    if (tid < G) {
        float v = rv[0][tid];
        int i = ri[0][tid];
#pragma unroll
        for (int w = 1; w < NW; ++w) {
            float ov = rv[w][tid];
            int oi = ri[w][tid];
            if (ov > v || (ov == v && oi < i)) { v = ov; i = oi; }
        }
        size_t o = ((size_t)b * G + tid) * CHUNKS + chunk;
        pval[o] = v;
        pidx[o] = i;
    }
}

// Phase 2: per-batch block; reduce chunk partials, gather matched preds, exact loss.
__global__ __launch_bounds__(64) void k_loss(const float* __restrict__ preds,
                                             const float* __restrict__ gt_boxes,
                                             const int* __restrict__ gt_cls,
                                             const float* __restrict__ pval,
                                             const int* __restrict__ pidx,
                                             float* __restrict__ partial) {
    const int b = blockIdx.x;
    const int tid = threadIdx.x;
    float contrib = 0.0f;
    if (tid < G) {
        const int g = tid;
        size_t base = ((size_t)b * G + g) * CHUNKS;
        float v = pval[base];
        int i = pidx[base];
#pragma unroll
        for (int c = 1; c < CHUNKS; ++c) {
            float ov = pval[base + c];
            int oi = pidx[base + c];
            if (ov > v || (ov == v && oi < i)) { v = ov; i = oi; }
        }
        const float* pr = preds + ((size_t)b * N + i) * D;
        const f32x4u p4 = *reinterpret_cast<const f32x4u*>(pr);
        const float* gb = gt_boxes + ((size_t)b * G + g) * 4;
        float ciou = ciou_exact(p4.x, p4.y, p4.z, p4.w, gb[0], gb[1], gb[2], gb[3]);
        float loss_box = 1.0f - ciou;
        float loss_obj = softplusf(-pr[4]);
        int cls = gt_cls[b * G + g];
        float loss_cls = softplusf(-pr[5 + cls]);
        contrib = 5.0f * loss_box + loss_obj + loss_cls;
    }
#pragma unroll
    for (int off = 32; off > 0; off >>= 1) contrib += __shfl_down(contrib, off);
    if (tid == 0) partial[b] = contrib;
}

// Phase 3: sum 64 per-batch partials into the scalar output.
__global__ __launch_bounds__(64) void k_final(const float* __restrict__ partial,
                                              float* __restrict__ out) {
    float v = partial[threadIdx.x];
#pragma unroll
    for (int off = 32; off > 0; off >>= 1) v += __shfl_down(v, off);
    if (threadIdx.x == 0) out[0] = v;
}

extern "C" void kernel_launch(void* const* d_in, const int* in_sizes, int n_in,
                              void* d_out, int out_size, void* d_ws, size_t ws_size,
                              hipStream_t stream) {
    const float* preds = (const float*)d_in[0];
    const float* gt_boxes = (const float*)d_in[1];
    const int* gt_cls = (const int*)d_in[2];
    float* out = (float*)d_out;

    float* pval = (float*)d_ws;  // B*G*CHUNKS f32
    int* pidx = (int*)((char*)d_ws + sizeof(float) * (size_t)B * G * CHUNKS);
    float* partial = (float*)((char*)d_ws + 2 * sizeof(float) * (size_t)B * G * CHUNKS);

    k_argmax<<<B * CHUNKS, BLK, 0, stream>>>(preds, gt_boxes, pval, pidx);
    k_loss<<<B, 64, 0, stream>>>(preds, gt_boxes, gt_cls, pval, pidx, partial);
    k_final<<<1, 64, 0, stream>>>(partial, out);
}

// Round 9
// 223.591 us; speedup vs baseline: 2.6853x; 1.0717x over previous
//
#include <hip/hip_runtime.h>
#include <math.h>

#ifndef INFINITY
#define INFINITY __builtin_inff()
#endif

#define EPS 1e-6f
#define K4PI2 0.405284734569351086f  // 4 / pi^2

constexpr int B = 64;
constexpr int N = 25200;
constexpr int D = 21;
constexpr int G = 32;
constexpr int CHUNKS = 16;
constexpr int CHUNK = N / CHUNKS;   // 1575 (exact: 16*1575 = 25200)
constexpr int BLK = 512;            // 8 waves
constexpr int TILE = 512;            // preds staged per LDS tile (== BLK)
constexpr int NW = BLK / 64;        // 8
constexpr int STREAMS = NW * 2;     // 16 pred-streams (2 per wave: half-wave each)
constexpr int NTILES = (CHUNK + TILE - 1) / TILE;  // 4 (last tile only 39 valid)

// dword-aligned vector load (pred rows are 84B-strided: only 4B-aligned)
typedef float f32x4u __attribute__((ext_vector_type(4), aligned(4)));

__device__ __forceinline__ float fastrcp(float x) {
    return __builtin_amdgcn_rcpf(x);  // ~1 ulp; phase-1 scores only feed argmax
}

__device__ __forceinline__ float softplusf(float x) {
    return fmaxf(x, 0.0f) + log1pf(expf(-fabsf(x)));  // stable log(1+e^x)
}

// Full-reference-order CIoU with IEEE division (only for the 2048 final terms).
__device__ __forceinline__ float ciou_exact(float p_cx, float p_cy, float pw, float ph,
                                            float g_cx, float g_cy, float gw, float gh) {
    float p_x1 = p_cx - pw * 0.5f, p_y1 = p_cy - ph * 0.5f;
    float p_x2 = p_cx + pw * 0.5f, p_y2 = p_cy + ph * 0.5f;
    float g_x1 = g_cx - gw * 0.5f, g_y1 = g_cy - gh * 0.5f;
    float g_x2 = g_cx + gw * 0.5f, g_y2 = g_cy + gh * 0.5f;
    float iw = fmaxf(fminf(p_x2, g_x2) - fmaxf(p_x1, g_x1), 0.0f);
    float ih = fmaxf(fminf(p_y2, g_y2) - fmaxf(p_y1, g_y1), 0.0f);
    float inter = iw * ih;
    float p_area = (p_x2 - p_x1) * (p_y2 - p_y1);
    float g_area = (g_x2 - g_x1) * (g_y2 - g_y1);
    float uni = p_area + g_area - inter;
    float iou = inter / (uni + EPS);
    float dx = p_cx - g_cx, dy = p_cy - g_cy;
    float cd = dx * dx + dy * dy;
    float ew = fmaxf(p_x2, g_x2) - fminf(p_x1, g_x1);
    float eh = fmaxf(p_y2, g_y2) - fminf(p_y1, g_y1);
    float ed = ew * ew + eh * eh;
    float dat = atanf(pw / ph) - atanf(gw / gh);
    float v = K4PI2 * (dat * dat);
    float alpha = v / (1.0f - iou + v + EPS);
    return iou - cd / (ed + EPS) - alpha * v;
}

// Phase 1: gt <-> lane (lane l owns gt l&31 in scalar regs). Preds staged in LDS,
// 32B each: [px1 py1 px2 py2] + [parea+EPS, atan(w/h), pcx, pcy]. Double-buffered:
// raw global load for tile k+1 issued BEFORE computing tile k (latency hidden),
// derive+LDS-write after; ONE barrier per tile. Inner loop trimmed to the valid
// pred count (no 23% NaN-padding waste on the 39-pred tail tile).
__global__ __launch_bounds__(BLK, 6) void k_argmax(const float* __restrict__ preds,
                                                   const float* __restrict__ gt_boxes,
                                                   float* __restrict__ pval,
                                                   int* __restrict__ pidx) {
    __shared__ float4 sP[2][TILE * 2];  // [buf][2*p]=corners, [2*p+1]={pareaE,pat,pcx,pcy}
    __shared__ float rv[NW][G];
    __shared__ int ri[NW][G];

    const int b = blockIdx.x / CHUNKS;
    const int chunk = blockIdx.x % CHUNKS;
    const int tid = threadIdx.x;
    const int lane = tid & 63;
    const int wid = tid >> 6;
    const int g = lane & 31;
    const int stream = wid * 2 + (lane >> 5);  // 0..15
    const int n0 = chunk * CHUNK;
    const float qnan = __builtin_nanf("");

    // per-lane gt constants (lanes l and l+32 duplicate gt l's regs — by design)
    const float4 gt4 = *reinterpret_cast<const float4*>(gt_boxes + ((size_t)b * G + g) * 4);
    const float gcx = gt4.x, gcy = gt4.y;
    const float gx1 = gcx - gt4.z * 0.5f, gy1 = gcy - gt4.w * 0.5f;
    const float gx2 = gcx + gt4.z * 0.5f, gy2 = gcy + gt4.w * 0.5f;
    const float garea = (gx2 - gx1) * (gy2 - gy1);
    const float gat = atanf(gt4.z / gt4.w);

    float bestv = -INFINITY;
    int besti = 0x7fffffff;

    // ---- prologue: stage tile 0 into buf 0 ----
    {
        const int p = tid;  // TILE == BLK
        if (p < CHUNK) {
            const f32x4u pr =
                *reinterpret_cast<const f32x4u*>(preds + ((size_t)b * N + n0 + p) * D);
            float cx = pr.x, cy = pr.y, w = pr.z, h = pr.w;
            float px1 = cx - w * 0.5f, py1 = cy - h * 0.5f;
            float px2 = cx + w * 0.5f, py2 = cy + h * 0.5f;
            sP[0][2 * tid] = make_float4(px1, py1, px2, py2);
            sP[0][2 * tid + 1] =
                make_float4((px2 - px1) * (py2 - py1) + EPS, atanf(w / h), cx, cy);
        } else {
            sP[0][2 * tid] = make_float4(qnan, qnan, qnan, qnan);
            sP[0][2 * tid + 1] = make_float4(qnan, qnan, qnan, qnan);
        }
    }
    __syncthreads();

    for (int k = 0; k < NTILES; ++k) {
        const int t0 = k * TILE;
        const int buf = k & 1;

        // ---- issue next tile's raw load NOW (completes under the compute below) ----
        f32x4u raw;
        bool have = false;
        if (k + 1 < NTILES) {
            const int p = t0 + TILE + tid;
            if (p < CHUNK) {
                raw = *reinterpret_cast<const f32x4u*>(preds + ((size_t)b * N + n0 + p) * D);
                have = true;
            }
        }

        // ---- compute: only the valid iteration count (tail tile: 3 iters, not 32) ----
        const int navail = (CHUNK - t0 < TILE) ? (CHUNK - t0) : TILE;
        const int iters = (navail + STREAMS - 1) / STREAMS;
        const int nbase = n0 + t0;
#pragma unroll 4
        for (int it = 0; it < iters; ++it) {
            const int pp = it * STREAMS + stream;  // uniform per half-wave -> broadcast
            const float4 A = sP[buf][2 * pp];
            const float4 Q = sP[buf][2 * pp + 1];
            float iw = fminf(A.z, gx2) - fmaxf(A.x, gx1);
            float ih = fminf(A.w, gy2) - fmaxf(A.y, gy1);
            float inter = fmaxf(iw, 0.0f) * fmaxf(ih, 0.0f);
            float uni = (garea + Q.x) - inter;
            float iou = inter * fastrcp(uni);
            float dx = Q.z - gcx, dy = Q.w - gcy;
            float cd = dx * dx + dy * dy;
            float ew = fmaxf(A.z, gx2) - fminf(A.x, gx1);
            float eh = fmaxf(A.w, gy2) - fminf(A.y, gy1);
            float ed = ew * ew + eh * eh + EPS;
            float dat = Q.y - gat;
            float v = K4PI2 * (dat * dat);
            float den = (1.0f + EPS) + v - iou;
            float ciou = iou - cd * fastrcp(ed) - (v * v) * fastrcp(den);
            // NaN (padding) compares false -> never selected
            if (ciou > bestv) { bestv = ciou; besti = nbase + pp; }
        }

        // ---- derive + write next tile into the other buffer, then ONE barrier ----
        if (k + 1 < NTILES) {
            const int nb = buf ^ 1;
            if (have) {
                float cx = raw.x, cy = raw.y, w = raw.z, h = raw.w;
                float px1 = cx - w * 0.5f, py1 = cy - h * 0.5f;
                float px2 = cx + w * 0.5f, py2 = cy + h * 0.5f;
                sP[nb][2 * tid] = make_float4(px1, py1, px2, py2);
                sP[nb][2 * tid + 1] =
                    make_float4((px2 - px1) * (py2 - py1) + EPS, atanf(w / h), cx, cy);
            } else {
                sP[nb][2 * tid] = make_float4(qnan, qnan, qnan, qnan);
                sP[nb][2 * tid + 1] = make_float4(qnan, qnan, qnan, qnan);
            }
        }
        __syncthreads();
    }

    // combine the two half-wave streams (same g, disjoint preds)
    {
        float ov = __shfl_down(bestv, 32);
        int oi = __shfl_down(besti, 32);
        if (ov > bestv || (ov == bestv && oi < besti)) { bestv = ov; besti = oi; }
        if (lane < 32) { rv[wid][g] = bestv; ri[wid][g] = besti; }
    }
    __syncthreads();

    if (tid < G) {
        float v = rv[0][tid];
        int i = ri[0][tid];
#pragma unroll
        for (int w = 1; w < NW; ++w) {
            float ov = rv[w][tid];
            int oi = ri[w][tid];
            if (ov > v || (ov == v && oi < i)) { v = ov; i = oi; }
        }
        size_t o = ((size_t)b * G + tid) * CHUNKS + chunk;
        pval[o] = v;
        pidx[o] = i;
    }
}

// Phase 2: per-batch block; reduce chunk partials, gather matched preds, exact loss.
__global__ __launch_bounds__(64) void k_loss(const float* __restrict__ preds,
                                             const float* __restrict__ gt_boxes,
                                             const int* __restrict__ gt_cls,
                                             const float* __restrict__ pval,
                                             const int* __restrict__ pidx,
                                             float* __restrict__ partial) {
    const int b = blockIdx.x;
    const int tid = threadIdx.x;
    float contrib = 0.0f;
    if (tid < G) {
        const int g = tid;
        size_t base = ((size_t)b * G + g) * CHUNKS;
        float v = pval[base];
        int i = pidx[base];
#pragma unroll
        for (int c = 1; c < CHUNKS; ++c) {
            float ov = pval[base + c];
            int oi = pidx[base + c];
            if (ov > v || (ov == v && oi < i)) { v = ov; i = oi; }
        }
        const float* pr = preds + ((size_t)b * N + i) * D;
        const f32x4u p4 = *reinterpret_cast<const f32x4u*>(pr);
        const float* gb = gt_boxes + ((size_t)b * G + g) * 4;
        float ciou = ciou_exact(p4.x, p4.y, p4.z, p4.w, gb[0], gb[1], gb[2], gb[3]);
        float loss_box = 1.0f - ciou;
        float loss_obj = softplusf(-pr[4]);
        int cls = gt_cls[b * G + g];
        float loss_cls = softplusf(-pr[5 + cls]);
        contrib = 5.0f * loss_box + loss_obj + loss_cls;
    }
#pragma unroll
    for (int off = 32; off > 0; off >>= 1) contrib += __shfl_down(contrib, off);
    if (tid == 0) partial[b] = contrib;
}

// Phase 3: sum 64 per-batch partials into the scalar output.
__global__ __launch_bounds__(64) void k_final(const float* __restrict__ partial,
                                              float* __restrict__ out) {
    float v = partial[threadIdx.x];
#pragma unroll
    for (int off = 32; off > 0; off >>= 1) v += __shfl_down(v, off);
    if (threadIdx.x == 0) out[0] = v;
}

extern "C" void kernel_launch(void* const* d_in, const int* in_sizes, int n_in,
                              void* d_out, int out_size, void* d_ws, size_t ws_size,
                              hipStream_t stream) {
    const float* preds = (const float*)d_in[0];
    const float* gt_boxes = (const float*)d_in[1];
    const int* gt_cls = (const int*)d_in[2];
    float* out = (float*)d_out;

    float* pval = (float*)d_ws;  // B*G*CHUNKS f32
    int* pidx = (int*)((char*)d_ws + sizeof(float) * (size_t)B * G * CHUNKS);
    float* partial = (float*)((char*)d_ws + 2 * sizeof(float) * (size_t)B * G * CHUNKS);

    k_argmax<<<B * CHUNKS, BLK, 0, stream>>>(preds, gt_boxes, pval, pidx);
    k_loss<<<B, 64, 0, stream>>>(preds, gt_boxes, gt_cls, pval, pidx, partial);
    k_final<<<1, 64, 0, stream>>>(partial, out);
}

// Round 12
// 214.776 us; speedup vs baseline: 2.7955x; 1.0410x over previous
//
#include <hip/hip_runtime.h>
#include <math.h>

#ifndef INFINITY
#define INFINITY __builtin_inff()
#endif

#define EPS 1e-6f
#define K4PI2 0.405284734569351086f  // 4 / pi^2

constexpr int B = 64;
constexpr int N = 25200;
constexpr int D = 21;
constexpr int G = 32;
constexpr int CHUNKS = 16;
constexpr int CHUNK = N / CHUNKS;   // 1575
constexpr int BLK = 512;            // 8 waves
constexpr int TILE = 512;           // preds per LDS tile (== BLK)
constexpr int NW = BLK / 64;        // 8
constexpr int STREAMS = NW * 2;     // 16 half-wave streams; each handles 2 preds/iter
constexpr int NTILES = (CHUNK + TILE - 1) / TILE;  // 4 (tail: 39 valid)
constexpr int NF = 8;               // LDS fields per pred

typedef float f2 __attribute__((ext_vector_type(2)));
// dword-aligned vector load (pred rows are 84B-strided: only 4B-aligned)
typedef float f32x4u __attribute__((ext_vector_type(4), aligned(4)));

__device__ __forceinline__ float fastrcp(float x) {
    return __builtin_amdgcn_rcpf(x);  // ~1 ulp; phase-1 scores only feed argmax
}
__device__ __forceinline__ f2 vmin2(f2 a, f2 b) { return __builtin_elementwise_min(a, b); }
__device__ __forceinline__ f2 vmax2(f2 a, f2 b) { return __builtin_elementwise_max(a, b); }

__device__ __forceinline__ float softplusf(float x) {
    return fmaxf(x, 0.0f) + log1pf(expf(-fabsf(x)));  // stable log(1+e^x)
}

// Full-reference-order CIoU with IEEE division (only for the 2048 final terms).
__device__ __forceinline__ float ciou_exact(float p_cx, float p_cy, float pw, float ph,
                                            float g_cx, float g_cy, float gw, float gh) {
    float p_x1 = p_cx - pw * 0.5f, p_y1 = p_cy - ph * 0.5f;
    float p_x2 = p_cx + pw * 0.5f, p_y2 = p_cy + ph * 0.5f;
    float g_x1 = g_cx - gw * 0.5f, g_y1 = g_cy - gh * 0.5f;
    float g_x2 = g_cx + gw * 0.5f, g_y2 = g_cy + gh * 0.5f;
    float iw = fmaxf(fminf(p_x2, g_x2) - fmaxf(p_x1, g_x1), 0.0f);
    float ih = fmaxf(fminf(p_y2, g_y2) - fmaxf(p_y1, g_y1), 0.0f);
    float inter = iw * ih;
    float p_area = (p_x2 - p_x1) * (p_y2 - p_y1);
    float g_area = (g_x2 - g_x1) * (g_y2 - g_y1);
    float uni = p_area + g_area - inter;
    float iou = inter / (uni + EPS);
    float dx = p_cx - g_cx, dy = p_cy - g_cy;
    float cd = dx * dx + dy * dy;
    float ew = fmaxf(p_x2, g_x2) - fminf(p_x1, g_x1);
    float eh = fmaxf(p_y2, g_y2) - fminf(p_y1, g_y1);
    float ed = ew * ew + eh * eh;
    float dat = atanf(pw / ph) - atanf(gw / gh);
    float v = K4PI2 * (dat * dat);
    float alpha = v / (1.0f - iou + v + EPS);
    return iou - cd / (ed + EPS) - alpha * v;
}

// Phase 1: gt <-> lane (lane l owns gt l&31 in scalar regs). Preds staged in LDS as
// per-field column arrays sF[buf][field][pred] (stride-1 b32 writes: conflict-free;
// b64 broadcast reads). Each lane-iter processes TWO preds as float2 -> v_pk_* packed
// f32 for the geometry; single-rcp merged CIoU: with U=union+eps, D2=(1+eps+v)U-I
// (all >0), ciou = (I*ed*D2 - cd*U*D2 - v^2*U*ed) / (U*ed*D2).
// Double-buffered staging (raw load for k+1 issued before compute of k), 1 barrier/tile.
__global__ __launch_bounds__(BLK, 4) void k_argmax(const float* __restrict__ preds,
                                                   const float* __restrict__ gt_boxes,
                                                   float* __restrict__ pval,
                                                   int* __restrict__ pidx) {
    // fields: 0 px1, 1 py1, 2 px2, 3 py2, 4 pcx, 5 pcy, 6 parea+EPS, 7 atan(w/h)
    __shared__ float sF[2][NF][TILE];
    __shared__ float rv[NW][G];
    __shared__ int ri[NW][G];

    const int b = blockIdx.x / CHUNKS;
    const int chunk = blockIdx.x % CHUNKS;
    const int tid = threadIdx.x;
    const int lane = tid & 63;
    const int wid = tid >> 6;
    const int g = lane & 31;
    const int stream = wid * 2 + (lane >> 5);  // 0..15
    const int n0 = chunk * CHUNK;
    const float qnan = __builtin_nanf("");

    // per-lane gt constants (lanes l and l+32 duplicate gt l's regs — by design)
    const float4 gt4 = *reinterpret_cast<const float4*>(gt_boxes + ((size_t)b * G + g) * 4);
    const float gcx = gt4.x, gcy = gt4.y;
    const float gx1 = gcx - gt4.z * 0.5f, gy1 = gcy - gt4.w * 0.5f;
    const float gx2 = gcx + gt4.z * 0.5f, gy2 = gcy + gt4.w * 0.5f;
    const float garea = (gx2 - gx1) * (gy2 - gy1);
    const float gat = atanf(gt4.z / gt4.w);
    // float2 splats for packed math
    const f2 gx1s = {gx1, gx1}, gy1s = {gy1, gy1}, gx2s = {gx2, gx2}, gy2s = {gy2, gy2};
    const f2 gcxs = {gcx, gcx}, gcys = {gcy, gcy}, gareas = {garea, garea};
    const f2 gats = {gat, gat};
    const f2 zs = {0.0f, 0.0f}, epss = {EPS, EPS};
    const f2 k4s = {K4PI2, K4PI2};
    const f2 opes = {1.0f + EPS, 1.0f + EPS};

    float bestv = -INFINITY;
    int besti = 0x7fffffff;

    // ---- prologue: stage tile 0 into buf 0 ----
    {
        const int p = tid;  // TILE == BLK
        if (p < CHUNK) {
            const f32x4u pr =
                *reinterpret_cast<const f32x4u*>(preds + ((size_t)b * N + n0 + p) * D);
            float cx = pr.x, cy = pr.y, w = pr.z, h = pr.w;
            float px1 = cx - w * 0.5f, py1 = cy - h * 0.5f;
            float px2 = cx + w * 0.5f, py2 = cy + h * 0.5f;
            sF[0][0][p] = px1; sF[0][1][p] = py1; sF[0][2][p] = px2; sF[0][3][p] = py2;
            sF[0][4][p] = cx;  sF[0][5][p] = cy;
            sF[0][6][p] = (px2 - px1) * (py2 - py1) + EPS;
            sF[0][7][p] = atanf(w / h);
        } else {
#pragma unroll
            for (int f = 0; f < NF; ++f) sF[0][f][p] = qnan;
        }
    }
    __syncthreads();

    for (int k = 0; k < NTILES; ++k) {
        const int t0 = k * TILE;
        const int buf = k & 1;

        // ---- issue next tile's raw load NOW (completes under the compute below) ----
        f32x4u raw;
        bool have = false;
        if (k + 1 < NTILES) {
            const int p = t0 + TILE + tid;
            if (p < CHUNK) {
                raw = *reinterpret_cast<const f32x4u*>(preds + ((size_t)b * N + n0 + p) * D);
                have = true;
            }
        }

        // ---- compute: 2 preds per lane-iter, packed f32 geometry ----
        const int navail = (CHUNK - t0 < TILE) ? (CHUNK - t0) : TILE;
        const int npairs = (navail + 1) >> 1;
        const int iters = (npairs + STREAMS - 1) / STREAMS;
        const int nbase = n0 + t0;
#pragma unroll 4
        for (int it = 0; it < iters; ++it) {
            const int q = it * STREAMS + stream;  // pair index; uniform per half-wave
            const int e = 2 * q;
            const f2 px1 = *(const f2*)&sF[buf][0][e];
            const f2 py1 = *(const f2*)&sF[buf][1][e];
            const f2 px2 = *(const f2*)&sF[buf][2][e];
            const f2 py2 = *(const f2*)&sF[buf][3][e];
            const f2 pcx = *(const f2*)&sF[buf][4][e];
            const f2 pcy = *(const f2*)&sF[buf][5][e];
            const f2 pae = *(const f2*)&sF[buf][6][e];
            const f2 pat = *(const f2*)&sF[buf][7][e];

            f2 iw = vmin2(px2, gx2s) - vmax2(px1, gx1s);
            f2 ih = vmin2(py2, gy2s) - vmax2(py1, gy1s);
            f2 I = vmax2(iw, zs) * vmax2(ih, zs);
            f2 U = (pae + gareas) - I;
            f2 dx = pcx - gcxs, dy = pcy - gcys;
            f2 cd = dx * dx + dy * dy;
            f2 ew = vmax2(px2, gx2s) - vmin2(px1, gx1s);
            f2 eh = vmax2(py2, gy2s) - vmin2(py1, gy1s);
            f2 ed = ew * ew + eh * eh + epss;
            f2 dat = pat - gats;
            f2 v = k4s * (dat * dat);
            f2 D2 = (opes + v) * U - I;
            f2 v2 = v * v;
            f2 edD2 = ed * D2;
            f2 Ued = U * ed;
            f2 UD2 = U * D2;
            f2 denom = Ued * D2;
            f2 numer = I * edD2 - cd * UD2 - v2 * Ued;

            // scalar tail: one rcp + select per pred (NaN padding never selected)
            float c0 = numer.x * fastrcp(denom.x);
            float c1 = numer.y * fastrcp(denom.y);
            if (c0 > bestv) { bestv = c0; besti = nbase + e; }
            if (c1 > bestv) { bestv = c1; besti = nbase + e + 1; }
        }

        // ---- derive + write next tile into the other buffer, then ONE barrier ----
        if (k + 1 < NTILES) {
            const int nb = buf ^ 1;
            const int p = tid;
            if (have) {
                float cx = raw.x, cy = raw.y, w = raw.z, h = raw.w;
                float px1 = cx - w * 0.5f, py1 = cy - h * 0.5f;
                float px2 = cx + w * 0.5f, py2 = cy + h * 0.5f;
                sF[nb][0][p] = px1; sF[nb][1][p] = py1; sF[nb][2][p] = px2; sF[nb][3][p] = py2;
                sF[nb][4][p] = cx;  sF[nb][5][p] = cy;
                sF[nb][6][p] = (px2 - px1) * (py2 - py1) + EPS;
                sF[nb][7][p] = atanf(w / h);
            } else {
#pragma unroll
                for (int f = 0; f < NF; ++f) sF[nb][f][p] = qnan;
            }
        }
        __syncthreads();
    }

    // combine the two half-wave streams (same g, disjoint preds)
    {
        float ov = __shfl_down(bestv, 32);
        int oi = __shfl_down(besti, 32);
        if (ov > bestv || (ov == bestv && oi < besti)) { bestv = ov; besti = oi; }
        if (lane < 32) { rv[wid][g] = bestv; ri[wid][g] = besti; }
    }
    __syncthreads();

    if (tid < G) {
        float v = rv[0][tid];
        int i = ri[0][tid];
#pragma unroll
        for (int w = 1; w < NW; ++w) {
            float ov = rv[w][tid];
            int oi = ri[w][tid];
            if (ov > v || (ov == v && oi < i)) { v = ov; i = oi; }
        }
        size_t o = ((size_t)b * G + tid) * CHUNKS + chunk;
        pval[o] = v;
        pidx[o] = i;
    }
}

// Phase 2: per-batch block; reduce chunk partials, gather matched preds, exact loss.
__global__ __launch_bounds__(64) void k_loss(const float* __restrict__ preds,
                                             const float* __restrict__ gt_boxes,
                                             const int* __restrict__ gt_cls,
                                             const float* __restrict__ pval,
                                             const int* __restrict__ pidx,
                                             float* __restrict__ partial) {
    const int b = blockIdx.x;
    const int tid = threadIdx.x;
    float contrib = 0.0f;
    if (tid < G) {
        const int g = tid;
        size_t base = ((size_t)b * G + g) * CHUNKS;
        float v = pval[base];
        int i = pidx[base];
#pragma unroll
        for (int c = 1; c < CHUNKS; ++c) {
            float ov = pval[base + c];
            int oi = pidx[base + c];
            if (ov > v || (ov == v && oi < i)) { v = ov; i = oi; }
        }
        const float* pr = preds + ((size_t)b * N + i) * D;
        const f32x4u p4 = *reinterpret_cast<const f32x4u*>(pr);
        const float* gb = gt_boxes + ((size_t)b * G + g) * 4;
        float ciou = ciou_exact(p4.x, p4.y, p4.z, p4.w, gb[0], gb[1], gb[2], gb[3]);
        float loss_box = 1.0f - ciou;
        float loss_obj = softplusf(-pr[4]);
        int cls = gt_cls[b * G + g];
        float loss_cls = softplusf(-pr[5 + cls]);
        contrib = 5.0f * loss_box + loss_obj + loss_cls;
    }
#pragma unroll
    for (int off = 32; off > 0; off >>= 1) contrib += __shfl_down(contrib, off);
    if (tid == 0) partial[b] = contrib;
}

// Phase 3: sum 64 per-batch partials into the scalar output.
__global__ __launch_bounds__(64) void k_final(const float* __restrict__ partial,
                                              float* __restrict__ out) {
    float v = partial[threadIdx.x];
#pragma unroll
    for (int off = 32; off > 0; off >>= 1) v += __shfl_down(v, off);
    if (threadIdx.x == 0) out[0] = v;
}

extern "C" void kernel_launch(void* const* d_in, const int* in_sizes, int n_in,
                              void* d_out, int out_size, void* d_ws, size_t ws_size,
                              hipStream_t stream) {
    const float* preds = (const float*)d_in[0];
    const float* gt_boxes = (const float*)d_in[1];
    const int* gt_cls = (const int*)d_in[2];
    float* out = (float*)d_out;

    float* pval = (float*)d_ws;  // B*G*CHUNKS f32
    int* pidx = (int*)((char*)d_ws + sizeof(float) * (size_t)B * G * CHUNKS);
    float* partial = (float*)((char*)d_ws + 2 * sizeof(float) * (size_t)B * G * CHUNKS);

    k_argmax<<<B * CHUNKS, BLK, 0, stream>>>(preds, gt_boxes, pval, pidx);
    k_loss<<<B, 64, 0, stream>>>(preds, gt_boxes, gt_cls, pval, pidx, partial);
    k_final<<<1, 64, 0, stream>>>(partial, out);
}